// Round 8
// baseline (745.648 us; speedup 1.0000x reference)
//
#include <hip/hip_runtime.h>

// ---------- helpers ----------
typedef __bf16 bf16x8 __attribute__((ext_vector_type(8)));
typedef float f32x16 __attribute__((ext_vector_type(16)));

__device__ __forceinline__ unsigned short f2bf(float f) {
  unsigned u = __float_as_uint(f);
  u += 0x7FFFu + ((u >> 16) & 1u);   // RNE
  return (unsigned short)(u >> 16);
}

#define NPTS 4096
#define LDX 576   // padded K for stage GEMM1, divisible by BK=64

// ---------- batched weight transpose+convert: 6 weights in one launch
// z<3: w1[z] fp32 [Ksrc][512] -> W1t bf16 [512][576]; z>=3: wr -> Wrt [512][512] with +I
__global__ __launch_bounds__(256) void convw6_kernel(
    const float* w0, const float* w1, const float* w2,
    const float* r0, const float* r1, const float* r2,
    unsigned short* d0, unsigned short* d1, unsigned short* d2,
    unsigned short* e0, unsigned short* e1, unsigned short* e2) {
  int z = blockIdx.z;
  const float* src; unsigned short* dst; int Ksrc, Kpad, addI;
  switch (z) {
    case 0: src = w0; dst = d0; Ksrc = 524; Kpad = 576; addI = 0; break;
    case 1: src = w1; dst = d1; Ksrc = 513; Kpad = 576; addI = 0; break;
    case 2: src = w2; dst = d2; Ksrc = 513; Kpad = 576; addI = 0; break;
    case 3: src = r0; dst = e0; Ksrc = 512; Kpad = 512; addI = 1; break;
    case 4: src = r1; dst = e1; Ksrc = 512; Kpad = 512; addI = 1; break;
    default: src = r2; dst = e2; Ksrc = 512; Kpad = 512; addI = 1; break;
  }
  int k0 = blockIdx.x * 32;
  if (k0 >= Kpad) return;
  __shared__ float tile[32][33];
  int n0 = blockIdx.y * 32;
  int tx = threadIdx.x & 31, ty = threadIdx.x >> 5;  // 32 x 8
#pragma unroll
  for (int r = 0; r < 32; r += 8) {
    int k = k0 + ty + r, n = n0 + tx;
    tile[ty + r][tx] = (k < Ksrc) ? src[(size_t)k * 512 + n] : 0.f;
  }
  __syncthreads();
#pragma unroll
  for (int r = 0; r < 32; r += 8) {
    int n = n0 + ty + r, k = k0 + tx;
    float v = tile[tx][ty + r];
    if (addI && n == k) v += 1.0f;   // fold residual identity into Wr
    dst[(size_t)n * Kpad + k] = f2bf(v);
  }
}

// ---------- latent fp32 [M][512] -> X bf16 cols 0..511 (row stride LDX)
__global__ __launch_bounds__(256) void conv_latent_kernel(const float* __restrict__ latent,
                                                          unsigned short* __restrict__ X) {
  size_t idx = (size_t)blockIdx.x * 256 + threadIdx.x;  // over M*128 float4 groups
  size_t m = idx >> 7;
  int c4 = (int)(idx & 127) * 4;
  float4 v = *(const float4*)(latent + m * 512 + c4);
  ushort4 o;
  o.x = f2bf(v.x); o.y = f2bf(v.y); o.z = f2bf(v.z); o.w = f2bf(v.w);
  *(ushort4*)(X + m * LDX + c4) = o;
}

// ---------- KNN: nearest non-self neighbor + local covariance -> X cols 512..543
__device__ __forceinline__ void merge1(float& v, int& j, int mk) {
  float ov = __shfl_xor(v, mk); int oj = __shfl_xor(j, mk);
  bool take = (ov > v) || (ov == v && oj < j);   // tie -> lower index (reference top_k)
  v = take ? ov : v; j = take ? oj : j;
}

__global__ __launch_bounds__(512) void knn_kernel(const float* __restrict__ rp,
                                                  unsigned short* __restrict__ X) {
  __shared__ float4 P[NPTS];  // x,y,z,-|p|^2  (64 KB)
  int b = blockIdx.y;
  const float* base = rp + (size_t)b * 3 * NPTS;
  for (int j = threadIdx.x; j < NPTS; j += 512) {
    float x = base[j], y = base[NPTS + j], z = base[2 * NPTS + j];
    float xx = __fadd_rn(__fadd_rn(__fmul_rn(x, x), __fmul_rn(y, y)), __fmul_rn(z, z));
    P[j] = make_float4(x, y, z, -xx);
  }
  __syncthreads();
  int wave = threadIdx.x >> 6, lane = threadIdx.x & 63;
  int grp = lane >> 4, slice = lane & 15;
  int il0 = wave * 8 + grp * 2;          // this lane's two points: il0, il0+1
  int ia = blockIdx.x * 64 + il0;
  int ib = ia + 1;
  float4 pa = P[ia], pb = P[ib];
  float ax = 2.f * pa.x, ay = 2.f * pa.y, az = 2.f * pa.z;
  float bx = 2.f * pb.x, by = 2.f * pb.y, bz = 2.f * pb.z;
  float va = -3.4e38f, vb = -3.4e38f;
  int ta = 0, tb = 0;
  int sta = ((ia & 15) == slice) ? (ia >> 4) : -1;   // self-iteration to poison
  int stb = ((ib & 15) == slice) ? (ib >> 4) : -1;
  const float4* pp = P + slice;
#pragma unroll 8
  for (int t = 0; t < NPTS / 16; ++t) {
    float4 pj = pp[t * 16];
    float ea = __builtin_fmaf(ax, pj.x, __builtin_fmaf(ay, pj.y,
               __builtin_fmaf(az, pj.z, pj.w)));
    float eb = __builtin_fmaf(bx, pj.x, __builtin_fmaf(by, pj.y,
               __builtin_fmaf(bz, pj.z, pj.w)));
    ea = (t == sta) ? -3.4e38f : ea;
    eb = (t == stb) ? -3.4e38f : eb;
    bool ca = ea > va; va = ca ? ea : va; ta = ca ? t : ta;
    bool cb = eb > vb; vb = cb ? eb : vb; tb = cb ? t : tb;
  }
  int ja = ta * 16 + slice, jb = tb * 16 + slice;
#pragma unroll
  for (int mk = 1; mk <= 8; mk <<= 1) {
    merge1(va, ja, mk);
    merge1(vb, jb, mk);
  }
  if (slice == 0) {
#pragma unroll
    for (int p = 0; p < 2; ++p) {
      float4 pi = (p == 0) ? pa : pb;
      float4 p1 = P[(p == 0) ? ja : jb];   // nearest non-self neighbor
      size_t row = (size_t)b * NPTS + ia + p;
      unsigned short* xp = X + row * LDX + 512;
      float vals[12] = { pi.x, pi.y, pi.z,
                         pi.x * p1.x, pi.x * p1.y, pi.x * p1.z,
                         pi.y * p1.x, pi.y * p1.y, pi.y * p1.z,
                         pi.z * p1.x, pi.z * p1.y, pi.z * p1.z };
#pragma unroll
      for (int k = 0; k < 12; ++k) xp[k] = f2bf(vals[k]);
#pragma unroll
      for (int k = 12; k < 32; ++k) xp[k] = 0;   // cols 524..543 (zero weights there)
    }
  }
}

// ---------- GEMMs: 32x32x16 MFMA, register-prefetch pipeline.
// __launch_bounds__(256,2): gfx950's UNIFIED VGPR/AGPR file means acc(64 AGPR) counts
// against the wave budget; bare launch_bounds targeted ~128 regs -> the int4 prefetch
// arrays spilled to scratch (round 7: WRITE_SIZE 245 MB of spill traffic). Cap at 2
// waves/EU (~256 regs) so pa/pb stay in VGPRs.
// LDS layout: row stride 72 u16 (144 B): measured SQ_LDS_BANK_CONFLICT = 0 (round 7).
#define BM 128
#define BN 128
#define BK 64
#define LDT 72   // u16 row stride (64 data + 8 pad)

__global__ __launch_bounds__(256, 2) void gemm_relu_kernel(
    const unsigned short* __restrict__ Xb, const unsigned short* __restrict__ Wt,
    const float* __restrict__ bias, unsigned short* __restrict__ H,
    int K, int ldx, int ldw) {
  __shared__ unsigned short As[BM * LDT];
  __shared__ unsigned short Bs[BN * LDT];
  const int t = threadIdx.x;
  const int wave = t >> 6, lane = t & 63;
  const int m0 = blockIdx.y * BM, n0 = blockIdx.x * BN;
  const int wm = (wave >> 1) * 64, wn = (wave & 1) * 64;
  const int l31 = lane & 31, hi = lane >> 5;
  int srow[4], sc[4];
#pragma unroll
  for (int r = 0; r < 4; ++r) { int id = t + r * 256; srow[r] = id >> 3; sc[r] = (id & 7) * 8; }
  f32x16 acc[2][2] = {};
  int4 pa[4], pb[4];
#pragma unroll
  for (int r = 0; r < 4; ++r) {
    pa[r] = *(const int4*)(Xb + (size_t)(m0 + srow[r]) * ldx + sc[r]);
    pb[r] = *(const int4*)(Wt + (size_t)(n0 + srow[r]) * ldw + sc[r]);
  }
#pragma unroll
  for (int r = 0; r < 4; ++r) {
    *(int4*)(As + srow[r] * LDT + sc[r]) = pa[r];
    *(int4*)(Bs + srow[r] * LDT + sc[r]) = pb[r];
  }
  __syncthreads();
  const int NK = K / BK;
  for (int kt = 0; kt < NK; ++kt) {
    if (kt + 1 < NK) {
      int ko = (kt + 1) * BK;
#pragma unroll
      for (int r = 0; r < 4; ++r) {
        pa[r] = *(const int4*)(Xb + (size_t)(m0 + srow[r]) * ldx + ko + sc[r]);
        pb[r] = *(const int4*)(Wt + (size_t)(n0 + srow[r]) * ldw + ko + sc[r]);
      }
    }
#pragma unroll
    for (int ks = 0; ks < 4; ++ks) {
      bf16x8 a[2], bb[2];
#pragma unroll
      for (int i = 0; i < 2; ++i)
        a[i] = *(const bf16x8*)(As + (wm + i * 32 + l31) * LDT + ks * 16 + hi * 8);
#pragma unroll
      for (int j = 0; j < 2; ++j)
        bb[j] = *(const bf16x8*)(Bs + (wn + j * 32 + l31) * LDT + ks * 16 + hi * 8);
#pragma unroll
      for (int i = 0; i < 2; ++i)
#pragma unroll
        for (int j = 0; j < 2; ++j)
          acc[i][j] = __builtin_amdgcn_mfma_f32_32x32x16_bf16(a[i], bb[j], acc[i][j], 0, 0, 0);
    }
    __syncthreads();
    if (kt + 1 < NK) {
#pragma unroll
      for (int r = 0; r < 4; ++r) {
        *(int4*)(As + srow[r] * LDT + sc[r]) = pa[r];
        *(int4*)(Bs + srow[r] * LDT + sc[r]) = pb[r];
      }
      __syncthreads();
    }
  }
  // epilogue: C/D layout col=lane&31, row=(reg&3)+8*(reg>>2)+4*(lane>>5)  [m74/m101]
#pragma unroll
  for (int j = 0; j < 2; ++j) {
    int col = n0 + wn + j * 32 + l31;
    float bv = bias[col];
#pragma unroll
    for (int i = 0; i < 2; ++i) {
#pragma unroll
      for (int rg = 0; rg < 16; ++rg) {
        int row = m0 + wm + i * 32 + (rg & 3) + 8 * (rg >> 2) + 4 * hi;
        float v = acc[i][j][rg] + bv;
        v = v > 0.f ? v : 0.f;
        H[(size_t)row * 512 + col] = f2bf(v);
      }
    }
  }
}

// ---------- GEMM2: h2 = relu(H1 @ (Wr+I) + br); stage_out[row] += h2 . w2  (atomic)
__global__ __launch_bounds__(256, 2) void gemm_res_kernel(
    const unsigned short* __restrict__ H1, const unsigned short* __restrict__ Wt,
    const float* __restrict__ br, const float* __restrict__ w2,
    float* __restrict__ so) {
  __shared__ unsigned short As[BM * LDT];
  __shared__ unsigned short Bs[BN * LDT];
  const int t = threadIdx.x;
  const int wave = t >> 6, lane = t & 63;
  const int m0 = blockIdx.y * BM, n0 = blockIdx.x * BN;
  const int wm = (wave >> 1) * 64, wn = (wave & 1) * 64;
  const int l31 = lane & 31, hi = lane >> 5;
  int srow[4], sc[4];
#pragma unroll
  for (int r = 0; r < 4; ++r) { int id = t + r * 256; srow[r] = id >> 3; sc[r] = (id & 7) * 8; }
  f32x16 acc[2][2] = {};
  int4 pa[4], pb[4];
#pragma unroll
  for (int r = 0; r < 4; ++r) {
    pa[r] = *(const int4*)(H1 + (size_t)(m0 + srow[r]) * 512 + sc[r]);
    pb[r] = *(const int4*)(Wt + (size_t)(n0 + srow[r]) * 512 + sc[r]);
  }
#pragma unroll
  for (int r = 0; r < 4; ++r) {
    *(int4*)(As + srow[r] * LDT + sc[r]) = pa[r];
    *(int4*)(Bs + srow[r] * LDT + sc[r]) = pb[r];
  }
  __syncthreads();
  for (int kt = 0; kt < 8; ++kt) {
    if (kt + 1 < 8) {
      int ko = (kt + 1) * BK;
#pragma unroll
      for (int r = 0; r < 4; ++r) {
        pa[r] = *(const int4*)(H1 + (size_t)(m0 + srow[r]) * 512 + ko + sc[r]);
        pb[r] = *(const int4*)(Wt + (size_t)(n0 + srow[r]) * 512 + ko + sc[r]);
      }
    }
#pragma unroll
    for (int ks = 0; ks < 4; ++ks) {
      bf16x8 a[2], bb[2];
#pragma unroll
      for (int i = 0; i < 2; ++i)
        a[i] = *(const bf16x8*)(As + (wm + i * 32 + l31) * LDT + ks * 16 + hi * 8);
#pragma unroll
      for (int j = 0; j < 2; ++j)
        bb[j] = *(const bf16x8*)(Bs + (wn + j * 32 + l31) * LDT + ks * 16 + hi * 8);
#pragma unroll
      for (int i = 0; i < 2; ++i)
#pragma unroll
        for (int j = 0; j < 2; ++j)
          acc[i][j] = __builtin_amdgcn_mfma_f32_32x32x16_bf16(a[i], bb[j], acc[i][j], 0, 0, 0);
    }
    __syncthreads();
    if (kt + 1 < 8) {
#pragma unroll
      for (int r = 0; r < 4; ++r) {
        *(int4*)(As + srow[r] * LDT + sc[r]) = pa[r];
        *(int4*)(Bs + srow[r] * LDT + sc[r]) = pb[r];
      }
      __syncthreads();
    }
  }
  float pr[2][16];
#pragma unroll
  for (int i = 0; i < 2; ++i)
#pragma unroll
    for (int rg = 0; rg < 16; ++rg) pr[i][rg] = 0.f;
#pragma unroll
  for (int j = 0; j < 2; ++j) {
    int col = n0 + wn + j * 32 + l31;
    float bv = br[col], wv = w2[col];
#pragma unroll
    for (int i = 0; i < 2; ++i)
#pragma unroll
      for (int rg = 0; rg < 16; ++rg) {
        float v = acc[i][j][rg] + bv;   // residual folded into Wr+I
        v = v > 0.f ? v : 0.f;
        pr[i][rg] += v * wv;
      }
  }
#pragma unroll
  for (int i = 0; i < 2; ++i)
#pragma unroll
    for (int rg = 0; rg < 16; ++rg) {
      float s = pr[i][rg];
      s += __shfl_xor(s, 1); s += __shfl_xor(s, 2); s += __shfl_xor(s, 4);
      s += __shfl_xor(s, 8); s += __shfl_xor(s, 16);
      if (l31 == 0) {
        int row = m0 + wm + i * 32 + (rg & 3) + 8 * (rg >> 2) + 4 * hi;
        atomicAdd(&so[row], s);
      }
    }
}

// ---------- small kernels ----------
__global__ __launch_bounds__(256) void init_so_kernel(float* so, const float* b2) {
  int m = blockIdx.x * 256 + threadIdx.x;
  so[m] = b2[0];
}
__global__ __launch_bounds__(256) void update_kernel(float* std_cum, float* so,
                                                     unsigned short* X,
                                                     const float* b2_next, int first) {
  int m = blockIdx.x * 256 + threadIdx.x;
  float s = so[m];
  if (!first) s += std_cum[m];
  std_cum[m] = s;
  unsigned short* xp = X + (size_t)m * LDX + 512;
  xp[0] = f2bf(s);
#pragma unroll
  for (int k = 1; k < 12; ++k) xp[k] = 0;
  so[m] = b2_next[0];
}
__global__ __launch_bounds__(256) void finalize_kernel(float* out, const float* std_cum,
                                                       const float* so) {
  int m = blockIdx.x * 256 + threadIdx.x;
  out[m] = std_cum[m] + so[m];
}

extern "C" void kernel_launch(void* const* d_in, const int* in_sizes, int n_in,
                              void* d_out, int out_size, void* d_ws, size_t ws_size,
                              hipStream_t stream) {
  const int B = 8, N = NPTS, M = B * N;
  const float* latent = (const float*)d_in[0];
  const float* rp = (const float*)d_in[1];
  const float* w1[3] = {(const float*)d_in[2], (const float*)d_in[8], (const float*)d_in[14]};
  const float* b1[3] = {(const float*)d_in[3], (const float*)d_in[9], (const float*)d_in[15]};
  const float* wr[3] = {(const float*)d_in[4], (const float*)d_in[10], (const float*)d_in[16]};
  const float* br[3] = {(const float*)d_in[5], (const float*)d_in[11], (const float*)d_in[17]};
  const float* w2[3] = {(const float*)d_in[6], (const float*)d_in[12], (const float*)d_in[18]};
  const float* b2[3] = {(const float*)d_in[7], (const float*)d_in[13], (const float*)d_in[19]};

  char* ws = (char*)d_ws;
  auto carve = [&](size_t bytes) {
    char* p = ws;
    ws += (bytes + 255) & ~(size_t)255;
    return p;
  };
  unsigned short* X  = (unsigned short*)carve((size_t)M * LDX * 2);
  unsigned short* H1 = (unsigned short*)carve((size_t)M * 512 * 2);
  unsigned short* W1t[3], *Wrt[3];
  for (int s = 0; s < 3; ++s) W1t[s] = (unsigned short*)carve((size_t)512 * LDX * 2);
  for (int s = 0; s < 3; ++s) Wrt[s] = (unsigned short*)carve((size_t)512 * 512 * 2);
  float* std_cum = (float*)carve((size_t)M * 4);
  float* so      = (float*)carve((size_t)M * 4);

  convw6_kernel<<<dim3(LDX / 32, 16, 6), 256, 0, stream>>>(
      w1[0], w1[1], w1[2], wr[0], wr[1], wr[2],
      W1t[0], W1t[1], W1t[2], Wrt[0], Wrt[1], Wrt[2]);
  conv_latent_kernel<<<(M * 128) / 256, 256, 0, stream>>>(latent, X);
  knn_kernel<<<dim3(N / 64, B), 512, 0, stream>>>(rp, X);
  init_so_kernel<<<M / 256, 256, 0, stream>>>(so, b2[0]);

  for (int s = 0; s < 3; ++s) {
    gemm_relu_kernel<<<dim3(4, M / BM), 256, 0, stream>>>(X, W1t[s], b1[s], H1, LDX, LDX, LDX);
    gemm_res_kernel<<<dim3(4, M / BM), 256, 0, stream>>>(H1, Wrt[s], br[s], w2[s], so);
    if (s < 2)
      update_kernel<<<M / 256, 256, 0, stream>>>(std_cum, so, X, b2[s + 1], s == 0 ? 1 : 0);
  }
  finalize_kernel<<<M / 256, 256, 0, stream>>>((float*)d_out, std_cum, so);
}

// Round 9
// 351.820 us; speedup vs baseline: 2.1194x; 2.1194x over previous
//
#include <hip/hip_runtime.h>

// ---------- helpers ----------
typedef __bf16 bf16x8 __attribute__((ext_vector_type(8)));
typedef float f32x16 __attribute__((ext_vector_type(16)));

__device__ __forceinline__ unsigned short f2bf(float f) {
  unsigned u = __float_as_uint(f);
  u += 0x7FFFu + ((u >> 16) & 1u);   // RNE
  return (unsigned short)(u >> 16);
}

__device__ __forceinline__ void gload_lds16(const void* g, void* l) {
  __builtin_amdgcn_global_load_lds((const __attribute__((address_space(1))) void*)g,
                                   (__attribute__((address_space(3))) void*)l,
                                   16, 0, 0);
}

#define NPTS 4096
#define LDX 576   // padded K for stage GEMM1, divisible by BK=64

// ---------- batched weight transpose+convert: 6 weights in one launch
// z<3: w1[z] fp32 [Ksrc][512] -> W1t bf16 [512][576]; z>=3: wr -> Wrt [512][512] with +I
__global__ __launch_bounds__(256) void convw6_kernel(
    const float* w0, const float* w1, const float* w2,
    const float* r0, const float* r1, const float* r2,
    unsigned short* d0, unsigned short* d1, unsigned short* d2,
    unsigned short* e0, unsigned short* e1, unsigned short* e2) {
  int z = blockIdx.z;
  const float* src; unsigned short* dst; int Ksrc, Kpad, addI;
  switch (z) {
    case 0: src = w0; dst = d0; Ksrc = 524; Kpad = 576; addI = 0; break;
    case 1: src = w1; dst = d1; Ksrc = 513; Kpad = 576; addI = 0; break;
    case 2: src = w2; dst = d2; Ksrc = 513; Kpad = 576; addI = 0; break;
    case 3: src = r0; dst = e0; Ksrc = 512; Kpad = 512; addI = 1; break;
    case 4: src = r1; dst = e1; Ksrc = 512; Kpad = 512; addI = 1; break;
    default: src = r2; dst = e2; Ksrc = 512; Kpad = 512; addI = 1; break;
  }
  int k0 = blockIdx.x * 32;
  if (k0 >= Kpad) return;
  __shared__ float tile[32][33];
  int n0 = blockIdx.y * 32;
  int tx = threadIdx.x & 31, ty = threadIdx.x >> 5;  // 32 x 8
#pragma unroll
  for (int r = 0; r < 32; r += 8) {
    int k = k0 + ty + r, n = n0 + tx;
    tile[ty + r][tx] = (k < Ksrc) ? src[(size_t)k * 512 + n] : 0.f;
  }
  __syncthreads();
#pragma unroll
  for (int r = 0; r < 32; r += 8) {
    int n = n0 + ty + r, k = k0 + tx;
    float v = tile[tx][ty + r];
    if (addI && n == k) v += 1.0f;   // fold residual identity into Wr
    dst[(size_t)n * Kpad + k] = f2bf(v);
  }
}

// ---------- latent fp32 [M][512] -> X bf16 cols 0..511 (row stride LDX)
__global__ __launch_bounds__(256) void conv_latent_kernel(const float* __restrict__ latent,
                                                          unsigned short* __restrict__ X) {
  size_t idx = (size_t)blockIdx.x * 256 + threadIdx.x;  // over M*128 float4 groups
  size_t m = idx >> 7;
  int c4 = (int)(idx & 127) * 4;
  float4 v = *(const float4*)(latent + m * 512 + c4);
  ushort4 o;
  o.x = f2bf(v.x); o.y = f2bf(v.y); o.z = f2bf(v.z); o.w = f2bf(v.w);
  *(ushort4*)(X + m * LDX + c4) = o;
}

// ---------- KNN: nearest non-self neighbor + local covariance -> X cols 512..543
__device__ __forceinline__ void merge1(float& v, int& j, int mk) {
  float ov = __shfl_xor(v, mk); int oj = __shfl_xor(j, mk);
  bool take = (ov > v) || (ov == v && oj < j);   // tie -> lower index (reference top_k)
  v = take ? ov : v; j = take ? oj : j;
}

__global__ __launch_bounds__(512) void knn_kernel(const float* __restrict__ rp,
                                                  unsigned short* __restrict__ X) {
  __shared__ float4 P[NPTS];  // x,y,z,-|p|^2  (64 KB)
  int b = blockIdx.y;
  const float* base = rp + (size_t)b * 3 * NPTS;
  for (int j = threadIdx.x; j < NPTS; j += 512) {
    float x = base[j], y = base[NPTS + j], z = base[2 * NPTS + j];
    float xx = __fadd_rn(__fadd_rn(__fmul_rn(x, x), __fmul_rn(y, y)), __fmul_rn(z, z));
    P[j] = make_float4(x, y, z, -xx);
  }
  __syncthreads();
  int wave = threadIdx.x >> 6, lane = threadIdx.x & 63;
  int grp = lane >> 4, slice = lane & 15;
  int il0 = wave * 8 + grp * 2;          // this lane's two points: il0, il0+1
  int ia = blockIdx.x * 64 + il0;
  int ib = ia + 1;
  float4 pa = P[ia], pb = P[ib];
  float ax = 2.f * pa.x, ay = 2.f * pa.y, az = 2.f * pa.z;
  float bx = 2.f * pb.x, by = 2.f * pb.y, bz = 2.f * pb.z;
  float va = -3.4e38f, vb = -3.4e38f;
  int ta = 0, tb = 0;
  int sta = ((ia & 15) == slice) ? (ia >> 4) : -1;   // self-iteration to poison
  int stb = ((ib & 15) == slice) ? (ib >> 4) : -1;
  const float4* pp = P + slice;
#pragma unroll 8
  for (int t = 0; t < NPTS / 16; ++t) {
    float4 pj = pp[t * 16];
    float ea = __builtin_fmaf(ax, pj.x, __builtin_fmaf(ay, pj.y,
               __builtin_fmaf(az, pj.z, pj.w)));
    float eb = __builtin_fmaf(bx, pj.x, __builtin_fmaf(by, pj.y,
               __builtin_fmaf(bz, pj.z, pj.w)));
    ea = (t == sta) ? -3.4e38f : ea;
    eb = (t == stb) ? -3.4e38f : eb;
    bool ca = ea > va; va = ca ? ea : va; ta = ca ? t : ta;
    bool cb = eb > vb; vb = cb ? eb : vb; tb = cb ? t : tb;
  }
  int ja = ta * 16 + slice, jb = tb * 16 + slice;
#pragma unroll
  for (int mk = 1; mk <= 8; mk <<= 1) {
    merge1(va, ja, mk);
    merge1(vb, jb, mk);
  }
  if (slice == 0) {
#pragma unroll
    for (int p = 0; p < 2; ++p) {
      float4 pi = (p == 0) ? pa : pb;
      float4 p1 = P[(p == 0) ? ja : jb];   // nearest non-self neighbor
      size_t row = (size_t)b * NPTS + ia + p;
      unsigned short* xp = X + row * LDX + 512;
      float vals[12] = { pi.x, pi.y, pi.z,
                         pi.x * p1.x, pi.x * p1.y, pi.x * p1.z,
                         pi.y * p1.x, pi.y * p1.y, pi.y * p1.z,
                         pi.z * p1.x, pi.z * p1.y, pi.z * p1.z };
#pragma unroll
      for (int k = 0; k < 12; ++k) xp[k] = f2bf(vals[k]);
#pragma unroll
      for (int k = 12; k < 32; ++k) xp[k] = 0;   // cols 524..543 (zero weights there)
    }
  }
}

// ---------- GEMMs: round-5 structure (global_load_lds + XOR-swizzle, NO prefetch regs)
// scaled to 512-thread blocks, BM=256 x BN=128: 8 waves/block, wave = 64x64 quadrant
// (2x2 of 32x32, 64 acc regs — same per-wave footprint as round 5). 2 resident blocks
// x 8 waves = 16 waves/CU: one block's MFMA phase overlaps the other's barrier drain.
// LDS: A 32 grp + B 16 grp, GRP=520 u16 (1040 B) -> 49.9 KB.
#define BM 256
#define BN 128
#define BK 64
#define GRP 520   // u16 per 8-row group (512 data + 8 pad)

__global__ __launch_bounds__(512) void gemm_relu_kernel(
    const unsigned short* __restrict__ Xb, const unsigned short* __restrict__ Wt,
    const float* __restrict__ bias, unsigned short* __restrict__ H,
    int K, int ldx, int ldw) {
  __shared__ unsigned short As[32 * GRP];
  __shared__ unsigned short Bs[16 * GRP];
  const int t = threadIdx.x;
  const int wave = t >> 6, lane = t & 63;
  const int m0 = blockIdx.y * BM, n0 = blockIdx.x * BN;
  const int wm = (wave >> 1) * 64, wn = (wave & 1) * 64;
  const int srow = lane >> 3;               // staging row within group (0..7)
  const int sslot = (lane & 7) ^ srow;      // permuted k-chunk this lane fetches
  const int l31 = lane & 31, hi = lane >> 5;
  const int w7 = l31 & 7, g2 = l31 >> 3;
  f32x16 acc[2][2] = {};
  for (int kt = 0; kt < K; kt += BK) {
#pragma unroll
    for (int r = 0; r < 4; ++r) {
      int ga = wave + r * 8;   // A groups 0..31
      gload_lds16(Xb + (size_t)(m0 + ga * 8 + srow) * ldx + kt + sslot * 8, As + ga * GRP);
    }
#pragma unroll
    for (int r = 0; r < 2; ++r) {
      int gb = wave + r * 8;   // B groups 0..15
      gload_lds16(Wt + (size_t)(n0 + gb * 8 + srow) * ldw + kt + sslot * 8, Bs + gb * GRP);
    }
    __syncthreads();
#pragma unroll
    for (int ks = 0; ks < 4; ++ks) {
      int qx = (ks * 2 + hi) ^ w7;
      bf16x8 a[2], bb[2];
#pragma unroll
      for (int i = 0; i < 2; ++i)
        a[i] = *(const bf16x8*)(As + ((wm >> 3) + i * 4 + g2) * GRP + w7 * 64 + qx * 8);
#pragma unroll
      for (int j = 0; j < 2; ++j)
        bb[j] = *(const bf16x8*)(Bs + ((wn >> 3) + j * 4 + g2) * GRP + w7 * 64 + qx * 8);
#pragma unroll
      for (int i = 0; i < 2; ++i)
#pragma unroll
        for (int j = 0; j < 2; ++j)
          acc[i][j] = __builtin_amdgcn_mfma_f32_32x32x16_bf16(a[i], bb[j], acc[i][j], 0, 0, 0);
    }
    __syncthreads();
  }
  // epilogue: C/D layout col=lane&31, row=(reg&3)+8*(reg>>2)+4*(lane>>5)  [m74/m101]
#pragma unroll
  for (int j = 0; j < 2; ++j) {
    int col = n0 + wn + j * 32 + l31;
    float bv = bias[col];
#pragma unroll
    for (int i = 0; i < 2; ++i) {
#pragma unroll
      for (int rg = 0; rg < 16; ++rg) {
        int row = m0 + wm + i * 32 + (rg & 3) + 8 * (rg >> 2) + 4 * hi;
        float v = acc[i][j][rg] + bv;
        v = v > 0.f ? v : 0.f;
        H[(size_t)row * 512 + col] = f2bf(v);
      }
    }
  }
}

// ---------- GEMM2: h2 = relu(H1 @ (Wr+I) + br); stage_out[row] += h2 . w2  (atomic)
__global__ __launch_bounds__(512) void gemm_res_kernel(
    const unsigned short* __restrict__ H1, const unsigned short* __restrict__ Wt,
    const float* __restrict__ br, const float* __restrict__ w2,
    float* __restrict__ so) {
  __shared__ unsigned short As[32 * GRP];
  __shared__ unsigned short Bs[16 * GRP];
  const int t = threadIdx.x;
  const int wave = t >> 6, lane = t & 63;
  const int m0 = blockIdx.y * BM, n0 = blockIdx.x * BN;
  const int wm = (wave >> 1) * 64, wn = (wave & 1) * 64;
  const int srow = lane >> 3;
  const int sslot = (lane & 7) ^ srow;
  const int l31 = lane & 31, hi = lane >> 5;
  const int w7 = l31 & 7, g2 = l31 >> 3;
  f32x16 acc[2][2] = {};
  for (int kt = 0; kt < 512; kt += BK) {
#pragma unroll
    for (int r = 0; r < 4; ++r) {
      int ga = wave + r * 8;
      gload_lds16(H1 + (size_t)(m0 + ga * 8 + srow) * 512 + kt + sslot * 8, As + ga * GRP);
    }
#pragma unroll
    for (int r = 0; r < 2; ++r) {
      int gb = wave + r * 8;
      gload_lds16(Wt + (size_t)(n0 + gb * 8 + srow) * 512 + kt + sslot * 8, Bs + gb * GRP);
    }
    __syncthreads();
#pragma unroll
    for (int ks = 0; ks < 4; ++ks) {
      int qx = (ks * 2 + hi) ^ w7;
      bf16x8 a[2], bb[2];
#pragma unroll
      for (int i = 0; i < 2; ++i)
        a[i] = *(const bf16x8*)(As + ((wm >> 3) + i * 4 + g2) * GRP + w7 * 64 + qx * 8);
#pragma unroll
      for (int j = 0; j < 2; ++j)
        bb[j] = *(const bf16x8*)(Bs + ((wn >> 3) + j * 4 + g2) * GRP + w7 * 64 + qx * 8);
#pragma unroll
      for (int i = 0; i < 2; ++i)
#pragma unroll
        for (int j = 0; j < 2; ++j)
          acc[i][j] = __builtin_amdgcn_mfma_f32_32x32x16_bf16(a[i], bb[j], acc[i][j], 0, 0, 0);
    }
    __syncthreads();
  }
  float pr[2][16];
#pragma unroll
  for (int i = 0; i < 2; ++i)
#pragma unroll
    for (int rg = 0; rg < 16; ++rg) pr[i][rg] = 0.f;
#pragma unroll
  for (int j = 0; j < 2; ++j) {
    int col = n0 + wn + j * 32 + l31;
    float bv = br[col], wv = w2[col];
#pragma unroll
    for (int i = 0; i < 2; ++i)
#pragma unroll
      for (int rg = 0; rg < 16; ++rg) {
        float v = acc[i][j][rg] + bv;   // residual folded into Wr+I
        v = v > 0.f ? v : 0.f;
        pr[i][rg] += v * wv;
      }
  }
#pragma unroll
  for (int i = 0; i < 2; ++i)
#pragma unroll
    for (int rg = 0; rg < 16; ++rg) {
      float s = pr[i][rg];
      s += __shfl_xor(s, 1); s += __shfl_xor(s, 2); s += __shfl_xor(s, 4);
      s += __shfl_xor(s, 8); s += __shfl_xor(s, 16);
      if (l31 == 0) {
        int row = m0 + wm + i * 32 + (rg & 3) + 8 * (rg >> 2) + 4 * hi;
        atomicAdd(&so[row], s);
      }
    }
}

// ---------- small kernels ----------
__global__ __launch_bounds__(256) void init_so_kernel(float* so, const float* b2) {
  int m = blockIdx.x * 256 + threadIdx.x;
  so[m] = b2[0];
}
__global__ __launch_bounds__(256) void update_kernel(float* std_cum, float* so,
                                                     unsigned short* X,
                                                     const float* b2_next, int first) {
  int m = blockIdx.x * 256 + threadIdx.x;
  float s = so[m];
  if (!first) s += std_cum[m];
  std_cum[m] = s;
  unsigned short* xp = X + (size_t)m * LDX + 512;
  xp[0] = f2bf(s);
#pragma unroll
  for (int k = 1; k < 12; ++k) xp[k] = 0;
  so[m] = b2_next[0];
}
__global__ __launch_bounds__(256) void finalize_kernel(float* out, const float* std_cum,
                                                       const float* so) {
  int m = blockIdx.x * 256 + threadIdx.x;
  out[m] = std_cum[m] + so[m];
}

extern "C" void kernel_launch(void* const* d_in, const int* in_sizes, int n_in,
                              void* d_out, int out_size, void* d_ws, size_t ws_size,
                              hipStream_t stream) {
  const int B = 8, N = NPTS, M = B * N;
  const float* latent = (const float*)d_in[0];
  const float* rp = (const float*)d_in[1];
  const float* w1[3] = {(const float*)d_in[2], (const float*)d_in[8], (const float*)d_in[14]};
  const float* b1[3] = {(const float*)d_in[3], (const float*)d_in[9], (const float*)d_in[15]};
  const float* wr[3] = {(const float*)d_in[4], (const float*)d_in[10], (const float*)d_in[16]};
  const float* br[3] = {(const float*)d_in[5], (const float*)d_in[11], (const float*)d_in[17]};
  const float* w2[3] = {(const float*)d_in[6], (const float*)d_in[12], (const float*)d_in[18]};
  const float* b2[3] = {(const float*)d_in[7], (const float*)d_in[13], (const float*)d_in[19]};

  char* ws = (char*)d_ws;
  auto carve = [&](size_t bytes) {
    char* p = ws;
    ws += (bytes + 255) & ~(size_t)255;
    return p;
  };
  unsigned short* X  = (unsigned short*)carve((size_t)M * LDX * 2);
  unsigned short* H1 = (unsigned short*)carve((size_t)M * 512 * 2);
  unsigned short* W1t[3], *Wrt[3];
  for (int s = 0; s < 3; ++s) W1t[s] = (unsigned short*)carve((size_t)512 * LDX * 2);
  for (int s = 0; s < 3; ++s) Wrt[s] = (unsigned short*)carve((size_t)512 * 512 * 2);
  float* std_cum = (float*)carve((size_t)M * 4);
  float* so      = (float*)carve((size_t)M * 4);

  convw6_kernel<<<dim3(LDX / 32, 16, 6), 256, 0, stream>>>(
      w1[0], w1[1], w1[2], wr[0], wr[1], wr[2],
      W1t[0], W1t[1], W1t[2], Wrt[0], Wrt[1], Wrt[2]);
  conv_latent_kernel<<<(M * 128) / 256, 256, 0, stream>>>(latent, X);
  knn_kernel<<<dim3(N / 64, B), 512, 0, stream>>>(rp, X);
  init_so_kernel<<<M / 256, 256, 0, stream>>>(so, b2[0]);

  for (int s = 0; s < 3; ++s) {
    gemm_relu_kernel<<<dim3(BN / 128 * 4, M / BM), 512, 0, stream>>>(X, W1t[s], b1[s], H1,
                                                                     LDX, LDX, LDX);
    gemm_res_kernel<<<dim3(4, M / BM), 512, 0, stream>>>(H1, Wrt[s], br[s], w2[s], so);
    if (s < 2)
      update_kernel<<<M / 256, 256, 0, stream>>>(std_cum, so, X, b2[s + 1], s == 0 ? 1 : 0);
  }
  finalize_kernel<<<M / 256, 256, 0, stream>>>((float*)d_out, std_cum, so);
}